// Round 1
// baseline (17631.673 us; speedup 1.0000x reference)
//
#include <hip/hip_runtime.h>
#include <hip/hip_bf16.h>

#define NB 256   // batch
#define NS 512   // seq len
#define NV 4     // vocab / decoder hidden
#define NH 512   // encoder hidden

typedef __bf16 bf16x8 __attribute__((ext_vector_type(8)));
typedef float  f32x4  __attribute__((ext_vector_type(4)));

__device__ __forceinline__ float fast_tanh(float x) {
    x = fminf(12.0f, fmaxf(-12.0f, x));
    float e = __expf(2.0f * x);
    return (e - 1.0f) / (e + 1.0f);
}

// ---------------------------------------------------------------------------
// Encoder: 256 WGs (one per CU), 16 groups x 16 members.
// Group g owns batch rows [16g,16g+16); member m owns H-slice [32m,32m+32).
// Weights live in registers as MFMA B-fragments. Iter i computes h1[i] and
// h2[i-1] (both depend only on iter i-1 outputs) -> ONE group barrier/iter.
// encoded = PRE-tanh of final h2 step (arctanh(tanh(z)) == z).
// ---------------------------------------------------------------------------
__global__ __launch_bounds__(256, 1) void encoder_kernel(
    const float* __restrict__ x,
    const float* __restrict__ eWih0, const float* __restrict__ eWhh0,
    const float* __restrict__ ebih0, const float* __restrict__ ebhh0,
    const float* __restrict__ eWih1, const float* __restrict__ eWhh1,
    const float* __restrict__ ebih1, const float* __restrict__ ebhh1,
    __bf16* __restrict__ H1, __bf16* __restrict__ H2,
    int* __restrict__ cnt, float* __restrict__ encoded)
{
    const int blk  = blockIdx.x;
    // members of a group share blk%8 -> same XCD (2 groups per XCD)
    const int g    = ((blk & 7) << 1) | ((blk >> 3) & 1);
    const int m    = blk >> 4;
    const int b0   = g * 16;
    const int n0   = m * 32;
    const int tid  = threadIdx.x;
    const int wid  = tid >> 6;
    const int lane = tid & 63;
    const int nt   = wid & 1;   // n sub-tile (16 cols)
    const int kh   = wid >> 1;  // k half (256)
    const int lmod = lane & 15;
    const int ldiv = lane >> 4;
    const int ncol = n0 + nt * 16 + lmod;   // this lane's output column
    const int kbase = kh * 256 + ldiv * 8;  // k offset for fragment loads

    // ---- pack weight B-fragments into registers (once) ----
    bf16x8 WB0[8], WB1[8], WB2[8];
    {
        const float* w0 = eWhh0 + (size_t)ncol * NH;
        const float* w1 = eWih1 + (size_t)ncol * NH;
        const float* w2 = eWhh1 + (size_t)ncol * NH;
#pragma unroll
        for (int c = 0; c < 8; ++c) {
            const int k0 = kbase + c * 32;
#pragma unroll
            for (int j = 0; j < 8; ++j) {
                WB0[c][j] = (__bf16)w0[k0 + j];
                WB1[c][j] = (__bf16)w1[k0 + j];
                WB2[c][j] = (__bf16)w2[k0 + j];
            }
        }
    }
    const float b01 = ebih0[ncol] + ebhh0[ncol];
    const float b1  = ebih1[ncol] + ebhh1[ncol];
    const float4 W0row = *(const float4*)(eWih0 + (size_t)ncol * NV);

    __shared__ f32x4 red[4][64];

    const int arow = b0 + lmod;  // A-fragment batch row for this lane

#pragma unroll 1
    for (int i = 0; i <= NS; ++i) {
        const int p_h1r = (i + 1) & 1;   // h1[i-1]
        const int p_h1w = i & 1;         // h1[i]
        const int p_h2r = i & 1;         // h2[i-2]
        const int p_h2w = (i + 1) & 1;   // h2[i-1]

        const __bf16* a1p = H1 + ((size_t)p_h1r * NB + arow) * NH + kbase;
        const __bf16* a2p = H2 + ((size_t)p_h2r * NB + arow) * NH + kbase;
        bf16x8 A1[8], A2[8];
#pragma unroll
        for (int c = 0; c < 8; ++c) A1[c] = *(const bf16x8*)(a1p + c * 32);
#pragma unroll
        for (int c = 0; c < 8; ++c) A2[c] = *(const bf16x8*)(a2p + c * 32);

        f32x4 acc1 = {0.f, 0.f, 0.f, 0.f};
        f32x4 acc2 = {0.f, 0.f, 0.f, 0.f};
#pragma unroll
        for (int c = 0; c < 8; ++c)
            acc1 = __builtin_amdgcn_mfma_f32_16x16x32_bf16(A1[c], WB0[c], acc1, 0, 0, 0);
#pragma unroll
        for (int c = 0; c < 8; ++c)
            acc2 = __builtin_amdgcn_mfma_f32_16x16x32_bf16(A1[c], WB1[c], acc2, 0, 0, 0);
#pragma unroll
        for (int c = 0; c < 8; ++c)
            acc2 = __builtin_amdgcn_mfma_f32_16x16x32_bf16(A2[c], WB2[c], acc2, 0, 0, 0);

        // cross-wave K-half reduction: kh==0 finalizes h1, kh==1 finalizes h2
        red[wid][lane] = (kh == 0) ? acc2 : acc1;
        __syncthreads();
        const f32x4 part = red[wid ^ 2][lane];

        if (kh == 0) {
            if (i < NS) {
                __bf16* dst = H1 + (size_t)p_h1w * NB * NH;
#pragma unroll
                for (int j = 0; j < 4; ++j) {
                    const int b = b0 + ldiv * 4 + j;
                    const float4 xv = *(const float4*)(x + ((size_t)b * NS + i) * NV);
                    float s = acc1[j] + part[j] + b01
                            + xv.x * W0row.x + xv.y * W0row.y
                            + xv.z * W0row.z + xv.w * W0row.w;
                    dst[(size_t)b * NH + ncol] = (__bf16)fast_tanh(s);
                }
            }
        } else {
            if (i >= 1) {
#pragma unroll
                for (int j = 0; j < 4; ++j) {
                    const int b = b0 + ldiv * 4 + j;
                    const float s = acc2[j] + part[j] + b1;
                    if (i == NS) encoded[(size_t)b * NH + ncol] = s;  // pre-tanh!
                    else H2[((size_t)p_h2w * NB + b) * NH + ncol] = (__bf16)fast_tanh(s);
                }
            }
        }

        if (i < NS) {
            __threadfence();             // release: drain stores (every thread)
            __syncthreads();
            if (tid == 0) {
                int* c = cnt + g * NS + i;
                __hip_atomic_fetch_add(c, 1, __ATOMIC_RELEASE, __HIP_MEMORY_SCOPE_AGENT);
                while (__hip_atomic_load(c, __ATOMIC_ACQUIRE, __HIP_MEMORY_SCOPE_AGENT) < 16)
                    __builtin_amdgcn_s_sleep(1);
            }
            __syncthreads();
            __builtin_amdgcn_fence(__ATOMIC_ACQUIRE, "agent");  // L1 inv per wave
        }
    }
}

// ---------------------------------------------------------------------------
// Batch-axis softmax stats per hidden column.
// ---------------------------------------------------------------------------
__global__ void colstats_kernel(const float* __restrict__ encoded,
                                float* __restrict__ colmax,
                                float* __restrict__ rsinv)
{
    const int h = blockIdx.x;
    const int lane = threadIdx.x;  // 64
    float v[4];
#pragma unroll
    for (int r = 0; r < 4; ++r) v[r] = encoded[(size_t)(lane + 64 * r) * NH + h];
    float mx = fmaxf(fmaxf(v[0], v[1]), fmaxf(v[2], v[3]));
#pragma unroll
    for (int s = 1; s < 64; s <<= 1) mx = fmaxf(mx, __shfl_xor(mx, s));
    float sum = 0.f;
#pragma unroll
    for (int r = 0; r < 4; ++r) sum += __expf(v[r] - mx);
#pragma unroll
    for (int s = 1; s < 64; s <<= 1) sum += __shfl_xor(sum, s);
    if (lane == 0) { colmax[h] = mx; rsinv[h] = 1.0f / sum; }
}

// ---------------------------------------------------------------------------
// Decoder: 16 WGs x 1 wave; lane = 4*local_batch + j. a1 in prologue,
// then 512-step tiny recurrence via __shfl (hidden dim = 4).
// ---------------------------------------------------------------------------
__global__ void decoder_kernel(
    const float* __restrict__ encoded,
    const float* __restrict__ colmax, const float* __restrict__ rsinv,
    const float* __restrict__ dWih0, const float* __restrict__ dWhh0,
    const float* __restrict__ dbih0, const float* __restrict__ dbhh0,
    const float* __restrict__ dWih1, const float* __restrict__ dWhh1,
    const float* __restrict__ dbih1, const float* __restrict__ dbhh1,
    float* __restrict__ out)
{
    const int lane = threadIdx.x;  // 64
    const int bl = lane >> 2, j = lane & 3;
    const int b = blockIdx.x * 16 + bl;

    // a1[b][j] = bih0[j] + sum_h softmax_batch(enc)[b,h] * Wih0[j,h]
    float a1 = dbih0[j];
    const float* er = encoded + (size_t)b * NH;
    const float* wr = dWih0 + (size_t)j * NH;
    for (int h = 0; h < NH; ++h)
        a1 += __expf(er[h] - colmax[h]) * rsinv[h] * wr[h];

    const float4 Whh0r = *(const float4*)(dWhh0 + j * 4);
    const float4 Wih1r = *(const float4*)(dWih1 + j * 4);
    const float4 Whh1r = *(const float4*)(dWhh1 + j * 4);
    const float c1 = a1 + dbhh0[j];
    const float c2 = dbih1[j] + dbhh1[j];
    float h1 = 0.f, h2 = 0.f;
    const int base = lane & ~3;
    float* op = out + (size_t)b * NS * NV + j;

#pragma unroll 1
    for (int t = 0; t < NS; ++t) {
        float s = c1;
        s += Whh0r.x * __shfl(h1, base + 0);
        s += Whh0r.y * __shfl(h1, base + 1);
        s += Whh0r.z * __shfl(h1, base + 2);
        s += Whh0r.w * __shfl(h1, base + 3);
        h1 = fast_tanh(s);
        float s2 = c2;
        s2 += Wih1r.x * __shfl(h1, base + 0) + Whh1r.x * __shfl(h2, base + 0);
        s2 += Wih1r.y * __shfl(h1, base + 1) + Whh1r.y * __shfl(h2, base + 1);
        s2 += Wih1r.z * __shfl(h1, base + 2) + Whh1r.z * __shfl(h2, base + 2);
        s2 += Wih1r.w * __shfl(h1, base + 3) + Whh1r.w * __shfl(h2, base + 3);
        h2 = fast_tanh(s2);
        op[(size_t)t * NV] = h2;
    }
}

extern "C" void kernel_launch(void* const* d_in, const int* in_sizes, int n_in,
                              void* d_out, int out_size, void* d_ws, size_t ws_size,
                              hipStream_t stream)
{
    const float* x     = (const float*)d_in[0];
    const float* eWih0 = (const float*)d_in[1];
    const float* eWhh0 = (const float*)d_in[2];
    const float* ebih0 = (const float*)d_in[3];
    const float* ebhh0 = (const float*)d_in[4];
    const float* eWih1 = (const float*)d_in[5];
    const float* eWhh1 = (const float*)d_in[6];
    const float* ebih1 = (const float*)d_in[7];
    const float* ebhh1 = (const float*)d_in[8];
    const float* dWih0 = (const float*)d_in[9];
    const float* dWhh0 = (const float*)d_in[10];
    const float* dbih0 = (const float*)d_in[11];
    const float* dbhh0 = (const float*)d_in[12];
    const float* dWih1 = (const float*)d_in[13];
    const float* dWhh1 = (const float*)d_in[14];
    const float* dbih1 = (const float*)d_in[15];
    const float* dbhh1 = (const float*)d_in[16];

    char* ws = (char*)d_ws;
    __bf16* H1      = (__bf16*)(ws);                               // 512 KB: [2][B][H]
    __bf16* H2      = (__bf16*)(ws + (1 << 19));                   // 512 KB
    int*    cnt     = (int*)  (ws + (1 << 20));                    // 32 KB barrier counters
    float*  encoded = (float*)(ws + (1 << 20) + (1 << 16));        // 512 KB
    float*  colmax  = (float*)(ws + (1 << 20) + (1 << 16) + (1 << 19));
    float*  rsinv   = colmax + NH;

    // zero h-state double buffers + barrier counters
    hipMemsetAsync(d_ws, 0, (1 << 20) + (1 << 15), stream);

    encoder_kernel<<<256, 256, 0, stream>>>(x, eWih0, eWhh0, ebih0, ebhh0,
                                            eWih1, eWhh1, ebih1, ebhh1,
                                            H1, H2, cnt, encoded);
    colstats_kernel<<<NH, 64, 0, stream>>>(encoded, colmax, rsinv);
    decoder_kernel<<<16, 64, 0, stream>>>(encoded, colmax, rsinv,
                                          dWih0, dWhh0, dbih0, dbhh0,
                                          dWih1, dWhh1, dbih1, dbhh1,
                                          (float*)d_out);
}

// Round 2
// 8320.193 us; speedup vs baseline: 2.1191x; 2.1191x over previous
//
#include <hip/hip_runtime.h>
#include <hip/hip_bf16.h>

#define NB 256   // batch
#define NS 512   // seq len
#define NV 4     // vocab
#define NH 512   // encoder hidden
#define CH 16    // steps per chunk
#define NCH 32   // chunks
#define NG 16    // batch groups (16 rows each)
#define NHELP 8  // helper WGs per group
#define RR 2     // ring depth (chunks)

typedef __bf16 bf16x8 __attribute__((ext_vector_type(8)));
typedef float  f32x4  __attribute__((ext_vector_type(4)));

// ---- workspace byte offsets ----
#define FLAGS_BYTES   4096
#define H1RING_OFF    8192
#define H1RING_BYTES  (NG*RR*CH*16384)            // 8 MB   [g][slot][t][ks16][lane64][8 bf16]
#define ZRING_OFF     (H1RING_OFF + H1RING_BYTES)
#define ZRING_BYTES   (NG*RR*CH*32768)            // 16 MB  [g][slot][t][gt32][lane64][f32x4]
#define ENC_OFF       (ZRING_OFF + ZRING_BYTES)
#define CM_OFF        (ENC_OFF + NB*NH*4)
#define RS_OFF        (CM_OFF + 2048)
// flags (int* F): hprod(g)=F[g*16]  bprog(g)=F[256+g*16]  zdone(g,c)=F[512+g*32+c]

__device__ __forceinline__ float fast_tanh(float x) {
    x = fminf(12.0f, fmaxf(-12.0f, x));
    float e = __expf(2.0f * x);
    return (e - 1.0f) / (e + 1.0f);
}

__device__ __forceinline__ int aload(int* p) {
    return __hip_atomic_load(p, __ATOMIC_ACQUIRE, __HIP_MEMORY_SCOPE_AGENT);
}

// physical byte offset of logical A-frag slot (bank-conflict swizzle)
__device__ __forceinline__ int swzb(int slot) {
    return (slot << 4) ^ (((slot >> 2) & 1) << 5);
}

extern "C" __global__ __launch_bounds__(256, 1)
void persist_kernel(const float* __restrict__ x,
                    const float* __restrict__ eWih0, const float* __restrict__ eWhh0,
                    const float* __restrict__ ebih0, const float* __restrict__ ebhh0,
                    const float* __restrict__ eWih1, const float* __restrict__ eWhh1,
                    const float* __restrict__ ebih1, const float* __restrict__ ebhh1,
                    char* __restrict__ ws)
{
    extern __shared__ char lds[];
    int*   F      = (int*)ws;
    char*  h1ring = ws + H1RING_OFF;
    char*  zring  = ws + ZRING_OFF;
    float* enc    = (float*)(ws + ENC_OFF);

    const int blk = blockIdx.x;
    const int tid = threadIdx.x;
    const int wq  = tid >> 6;      // wave id 0..3
    const int l   = tid & 63;      // lane
    const int lm  = l & 15;
    const int q   = l >> 4;        // 0..3
    const int rdoff = (l << 4) ^ (((l >> 2) & 1) << 5);  // swizzled read byte off
    const int rho   = l ^ (((l >> 2) & 1) << 1);         // logical slot at phys slot l

    if (blk < 2 * NG) {
        // =========== chain roles: A (layer-0 recurrence) / B (layer-1 recurrence) ===========
        const bool isA = (blk < NG);
        const int  g   = isA ? blk : blk - NG;
        const float* Whh = isA ? eWhh0 : eWhh1;

        // LDS: [0,32768) h-state double buffer (swizzled A-frag layout, 16 KB each)
        //      [32768,163840) 4 K-steps of B-frags: [ks4][gt32][lane64][16B]
        char* HS = lds;
        char* WL = lds + 32768;

        // zero h-state
        {
            bf16x8 z8;
#pragma unroll
            for (int j = 0; j < 8; ++j) z8[j] = (__bf16)0.f;
            for (int o = tid; o < 2048; o += 256) *(bf16x8*)(HS + o * 16) = z8;
        }

        // ---- register/LDS-resident weights ----
        bf16x8 WR[12][8];
        bf16x8 EB[8];
        float  bias[8];
#pragma unroll
        for (int n = 0; n < 8; ++n) {
            const int col = wq * 128 + n * 16 + lm;
            const float* wrow = Whh + (size_t)col * NH;
#pragma unroll
            for (int ks = 0; ks < 12; ++ks) {
                const float* p = wrow + ks * 32 + q * 8;
#pragma unroll
                for (int j = 0; j < 8; ++j) WR[ks][n][j] = (__bf16)p[j];
            }
#pragma unroll
            for (int ks = 12; ks < 16; ++ks) {
                const float* p = wrow + ks * 32 + q * 8;
                bf16x8 tmp;
#pragma unroll
                for (int j = 0; j < 8; ++j) tmp[j] = (__bf16)p[j];
                *(bf16x8*)(WL + (((ks - 12) * 32 + wq * 8 + n) * 64 + l) * 16) = tmp;
            }
#pragma unroll
            for (int j = 0; j < 8; ++j) EB[n][j] = (__bf16)0.f;
            if (isA) {
                if (q == 0) {
                    const float4 w0 = *(const float4*)(eWih0 + (size_t)col * NV);
                    EB[n][0] = (__bf16)w0.x; EB[n][1] = (__bf16)w0.y;
                    EB[n][2] = (__bf16)w0.z; EB[n][3] = (__bf16)w0.w;
                }
                bias[n] = ebih0[col] + ebhh0[col];
            } else {
                bias[n] = 0.f;  // B: z already contains biases
            }
        }
        __syncthreads();

#pragma unroll 1
        for (int c = 0; c < NCH; ++c) {
            // ---- chunk-entry sync ----
            if (isA) {
                if (c >= RR) {  // backpressure: helpers must have consumed chunk c-RR
                    if (tid == 0)
                        while (aload(&F[512 + g * 32 + (c - RR)]) < NHELP)
                            __builtin_amdgcn_s_sleep(2);
                    __syncthreads();
                }
            } else {
                if (tid == 0)
                    while (aload(&F[512 + g * 32 + c]) < NHELP)
                        __builtin_amdgcn_s_sleep(2);
                __syncthreads();
                __builtin_amdgcn_fence(__ATOMIC_ACQUIRE, "agent");
            }

            char* rsl = h1ring + (size_t)(g * RR + (c & 1)) * CH * 16384;
            char* zsl = zring  + (size_t)(g * RR + (c & 1)) * CH * 32768;

            f32x4 zn[8];
            if (!isA) {
#pragma unroll
                for (int n = 0; n < 8; ++n)
                    zn[n] = *(const f32x4*)(zsl + ((wq * 8 + n) * 64 + l) * 16);
            }

#pragma unroll 1
            for (int t = 0; t < CH; ++t) {
                const int i  = c * CH + t;
                const int rb = t & 1;
                const char* hsr = HS + rb * 16384;
                char*       hsw = HS + (rb ^ 1) * 16384;

                f32x4 acc[8];
                bf16x8 xa;
                if (isA) {
#pragma unroll
                    for (int n = 0; n < 8; ++n)
                        acc[n] = (f32x4){bias[n], bias[n], bias[n], bias[n]};
                    const float4 xv = *(const float4*)(x + ((size_t)(g * 16 + lm) * NS + i) * NV);
#pragma unroll
                    for (int j = 0; j < 8; ++j) xa[j] = (__bf16)0.f;
                    if (q == 0) {
                        xa[0] = (__bf16)xv.x; xa[1] = (__bf16)xv.y;
                        xa[2] = (__bf16)xv.z; xa[3] = (__bf16)xv.w;
                    }
                } else {
#pragma unroll
                    for (int n = 0; n < 8; ++n) acc[n] = zn[n];
                    if (t + 1 < CH) {
#pragma unroll
                        for (int n = 0; n < 8; ++n)
                            zn[n] = *(const f32x4*)(zsl + (size_t)(t + 1) * 32768 +
                                                    ((wq * 8 + n) * 64 + l) * 16);
                    }
                }

                // ---- 16 main K-steps ----
#pragma unroll
                for (int ks = 0; ks < 12; ++ks) {
                    const bf16x8 af = *(const bf16x8*)(hsr + ks * 1024 + rdoff);
#pragma unroll
                    for (int n = 0; n < 8; ++n)
                        acc[n] = __builtin_amdgcn_mfma_f32_16x16x32_bf16(af, WR[ks][n], acc[n], 0, 0, 0);
                }
#pragma unroll
                for (int ks = 12; ks < 16; ++ks) {
                    const bf16x8 af = *(const bf16x8*)(hsr + ks * 1024 + rdoff);
#pragma unroll
                    for (int n = 0; n < 8; ++n) {
                        const bf16x8 bf = *(const bf16x8*)(WL + (((ks - 12) * 32 + wq * 8 + n) * 64 + l) * 16);
                        acc[n] = __builtin_amdgcn_mfma_f32_16x16x32_bf16(af, bf, acc[n], 0, 0, 0);
                    }
                }
                if (isA) {  // x @ Wih0^T  (extension K-step)
#pragma unroll
                    for (int n = 0; n < 8; ++n)
                        acc[n] = __builtin_amdgcn_mfma_f32_16x16x32_bf16(xa, EB[n], acc[n], 0, 0, 0);
                }

                // ---- epilogue ----
                if (!isA && i == NS - 1) {
                    // encoded = PRE-tanh (arctanh(tanh(s)) == s)
#pragma unroll
                    for (int n = 0; n < 8; ++n) {
                        const int col = wq * 128 + n * 16 + lm;
#pragma unroll
                        for (int jr = 0; jr < 4; ++jr)
                            enc[(size_t)(g * 16 + q * 4 + jr) * NH + col] = acc[n][jr];
                    }
                } else {
#pragma unroll
                    for (int n = 0; n < 8; ++n) {
                        const int col = wq * 128 + n * 16 + lm;
                        const int ks  = col >> 5;
                        const int cq  = (col >> 3) & 3;
                        const int bo  = (col & 7) * 2;
#pragma unroll
                        for (int jr = 0; jr < 4; ++jr) {
                            const float th = fast_tanh(acc[n][jr]);
                            const int slot = (q * 4 + jr) | (cq << 4);
                            *(__bf16*)(hsw + ks * 1024 + swzb(slot) + bo) = (__bf16)th;
                        }
                    }
                }
                __syncthreads();  // hsw complete for all waves

                if (isA) {
                    // copy new h1 (LDS, swizzled) -> ring (global, logical-linear)
                    char* rdst = rsl + (size_t)t * 16384;
#pragma unroll
                    for (int kk = 0; kk < 4; ++kk) {
                        const int ks = wq * 4 + kk;
                        const bf16x8 v = *(const bf16x8*)(hsw + ks * 1024 + l * 16);
                        *(bf16x8*)(rdst + ks * 1024 + rho * 16) = v;
                    }
                }
            }

            // ---- chunk-exit publish ----
            if (isA) {
                __threadfence();
                __syncthreads();
                if (tid == 0)
                    __hip_atomic_store(&F[g * 16], c + 1, __ATOMIC_RELEASE, __HIP_MEMORY_SCOPE_AGENT);
            } else {
                if (tid == 0)
                    __hip_atomic_store(&F[256 + g * 16], c + 1, __ATOMIC_RELEASE, __HIP_MEMORY_SCOPE_AGENT);
            }
        }
    } else {
        // =========== helper: z[t] = h1[t] @ Wih1^T + (bih1+bhh1) ===========
        const int hid = blk - 2 * NG;
        const int g   = hid >> 3;
        const int hh  = hid & 7;
        const int gt  = hh * 4 + wq;          // global n-tile 0..31
        const int col = gt * 16 + lm;

        bf16x8 WH[16];
#pragma unroll
        for (int ks = 0; ks < 16; ++ks) {
            const float* p = eWih1 + (size_t)col * NH + ks * 32 + q * 8;
#pragma unroll
            for (int j = 0; j < 8; ++j) WH[ks][j] = (__bf16)p[j];
        }
        const float bv = ebih1[col] + ebhh1[col];

#pragma unroll 1
        for (int c = 0; c < NCH; ++c) {
            if (tid == 0) {
                while (aload(&F[g * 16]) < c + 1) __builtin_amdgcn_s_sleep(2);
                if (c >= RR)
                    while (aload(&F[256 + g * 16]) < c - 1) __builtin_amdgcn_s_sleep(2);
            }
            __syncthreads();
            __builtin_amdgcn_fence(__ATOMIC_ACQUIRE, "agent");

            const char* rsl = h1ring + (size_t)(g * RR + (c & 1)) * CH * 16384;
            char*       zs  = zring  + (size_t)(g * RR + (c & 1)) * CH * 32768;

            bf16x8 af[16], nf[16];
#pragma unroll
            for (int ks = 0; ks < 16; ++ks)
                af[ks] = *(const bf16x8*)(rsl + ks * 1024 + l * 16);
#pragma unroll 1
            for (int t = 0; t < CH; ++t) {
                if (t + 1 < CH) {
#pragma unroll
                    for (int ks = 0; ks < 16; ++ks)
                        nf[ks] = *(const bf16x8*)(rsl + (size_t)(t + 1) * 16384 + ks * 1024 + l * 16);
                }
                f32x4 a = (f32x4){bv, bv, bv, bv};
#pragma unroll
                for (int ks = 0; ks < 16; ++ks)
                    a = __builtin_amdgcn_mfma_f32_16x16x32_bf16(af[ks], WH[ks], a, 0, 0, 0);
                *(f32x4*)(zs + (size_t)t * 32768 + (gt * 64 + l) * 16) = a;
                if (t + 1 < CH) {
#pragma unroll
                    for (int ks = 0; ks < 16; ++ks) af[ks] = nf[ks];
                }
            }
            __threadfence();
            __syncthreads();
            if (tid == 0)
                __hip_atomic_fetch_add(&F[512 + g * 32 + c], 1, __ATOMIC_RELEASE, __HIP_MEMORY_SCOPE_AGENT);
        }
    }
}

// ---------------------------------------------------------------------------
// Batch-axis softmax stats per hidden column.
// ---------------------------------------------------------------------------
__global__ void colstats_kernel(const float* __restrict__ encoded,
                                float* __restrict__ colmax,
                                float* __restrict__ rsinv)
{
    const int h = blockIdx.x;
    const int lane = threadIdx.x;  // 64
    float v[4];
#pragma unroll
    for (int r = 0; r < 4; ++r) v[r] = encoded[(size_t)(lane + 64 * r) * NH + h];
    float mx = fmaxf(fmaxf(v[0], v[1]), fmaxf(v[2], v[3]));
#pragma unroll
    for (int s = 1; s < 64; s <<= 1) mx = fmaxf(mx, __shfl_xor(mx, s));
    float sum = 0.f;
#pragma unroll
    for (int r = 0; r < 4; ++r) sum += __expf(v[r] - mx);
#pragma unroll
    for (int s = 1; s < 64; s <<= 1) sum += __shfl_xor(sum, s);
    if (lane == 0) { colmax[h] = mx; rsinv[h] = 1.0f / sum; }
}

// ---------------------------------------------------------------------------
// Decoder: 16 WGs x 1 wave; lane = 4*local_batch + j.
// ---------------------------------------------------------------------------
__global__ void decoder_kernel(
    const float* __restrict__ encoded,
    const float* __restrict__ colmax, const float* __restrict__ rsinv,
    const float* __restrict__ dWih0, const float* __restrict__ dWhh0,
    const float* __restrict__ dbih0, const float* __restrict__ dbhh0,
    const float* __restrict__ dWih1, const float* __restrict__ dWhh1,
    const float* __restrict__ dbih1, const float* __restrict__ dbhh1,
    float* __restrict__ out)
{
    const int lane = threadIdx.x;  // 64
    const int bl = lane >> 2, j = lane & 3;
    const int b = blockIdx.x * 16 + bl;

    float a1 = dbih0[j];
    const float* er = encoded + (size_t)b * NH;
    const float* wr = dWih0 + (size_t)j * NH;
    for (int h = 0; h < NH; ++h)
        a1 += __expf(er[h] - colmax[h]) * rsinv[h] * wr[h];

    const float4 Whh0r = *(const float4*)(dWhh0 + j * 4);
    const float4 Wih1r = *(const float4*)(dWih1 + j * 4);
    const float4 Whh1r = *(const float4*)(dWhh1 + j * 4);
    const float c1 = a1 + dbhh0[j];
    const float c2 = dbih1[j] + dbhh1[j];
    float h1 = 0.f, h2 = 0.f;
    const int base = lane & ~3;
    float* op = out + (size_t)b * NS * NV + j;

#pragma unroll 1
    for (int t = 0; t < NS; ++t) {
        float s = c1;
        s += Whh0r.x * __shfl(h1, base + 0);
        s += Whh0r.y * __shfl(h1, base + 1);
        s += Whh0r.z * __shfl(h1, base + 2);
        s += Whh0r.w * __shfl(h1, base + 3);
        h1 = fast_tanh(s);
        float s2 = c2;
        s2 += Wih1r.x * __shfl(h1, base + 0) + Whh1r.x * __shfl(h2, base + 0);
        s2 += Wih1r.y * __shfl(h1, base + 1) + Whh1r.y * __shfl(h2, base + 1);
        s2 += Wih1r.z * __shfl(h1, base + 2) + Whh1r.z * __shfl(h2, base + 2);
        s2 += Wih1r.w * __shfl(h1, base + 3) + Whh1r.w * __shfl(h2, base + 3);
        h2 = fast_tanh(s2);
        op[(size_t)t * NV] = h2;
    }
}

extern "C" void kernel_launch(void* const* d_in, const int* in_sizes, int n_in,
                              void* d_out, int out_size, void* d_ws, size_t ws_size,
                              hipStream_t stream)
{
    const float* x     = (const float*)d_in[0];
    const float* eWih0 = (const float*)d_in[1];
    const float* eWhh0 = (const float*)d_in[2];
    const float* ebih0 = (const float*)d_in[3];
    const float* ebhh0 = (const float*)d_in[4];
    const float* eWih1 = (const float*)d_in[5];
    const float* eWhh1 = (const float*)d_in[6];
    const float* ebih1 = (const float*)d_in[7];
    const float* ebhh1 = (const float*)d_in[8];
    const float* dWih0 = (const float*)d_in[9];
    const float* dWhh0 = (const float*)d_in[10];
    const float* dbih0 = (const float*)d_in[11];
    const float* dbhh0 = (const float*)d_in[12];
    const float* dWih1 = (const float*)d_in[13];
    const float* dWhh1 = (const float*)d_in[14];
    const float* dbih1 = (const float*)d_in[15];
    const float* dbhh1 = (const float*)d_in[16];

    char*  ws     = (char*)d_ws;
    float* enc    = (float*)(ws + ENC_OFF);
    float* colmax = (float*)(ws + CM_OFF);
    float* rsinv  = (float*)(ws + RS_OFF);

    // opt into 160 KiB dynamic LDS (deterministic, idempotent)
    hipFuncSetAttribute((const void*)persist_kernel,
                        hipFuncAttributeMaxDynamicSharedMemorySize, 163840);

    // zero flags region
    hipMemsetAsync(d_ws, 0, FLAGS_BYTES, stream);

    persist_kernel<<<2 * NG + NG * NHELP, 256, 163840, stream>>>(
        x, eWih0, eWhh0, ebih0, ebhh0, eWih1, eWhh1, ebih1, ebhh1, ws);

    colstats_kernel<<<NH, 64, 0, stream>>>(enc, colmax, rsinv);
    decoder_kernel<<<NG, 64, 0, stream>>>(enc, colmax, rsinv,
                                          dWih0, dWhh0, dbih0, dbhh0,
                                          dWih1, dWhh1, dbih1, dbhh1,
                                          (float*)d_out);
}

// Round 3
// 5862.469 us; speedup vs baseline: 3.0076x; 1.4192x over previous
//
#include <hip/hip_runtime.h>
#include <hip/hip_bf16.h>

#define NB 256   // batch
#define NS 512   // seq len
#define NV 4     // vocab
#define NH 512   // encoder hidden
#define CH 16    // steps per chunk
#define NCH 32   // chunks

typedef __bf16 bf16x8 __attribute__((ext_vector_type(8)));
typedef float  f32x4  __attribute__((ext_vector_type(4)));

// ---- workspace byte offsets ----
// h1buf: [g][parity][t][ks16][lane64][16B]   2*16*16*16KB = 8 MB
// zbuf : [g][parity][t][gt32][lane64][16B]   2*16*16*32KB = 16 MB
// hsave: [role][g] 16KB raw LDS state        512 KB
// enc  : [B][H] f32                          512 KB
#define H1BUF_OFF  0
#define ZBUF_OFF   (8u << 20)
#define HSAVE_OFF  (24u << 20)
#define ENC_OFF    ((24u << 20) + (1u << 19))
#define CM_OFF     (ENC_OFF + NB*NH*4)
#define RS_OFF     (CM_OFF + 2048)

__device__ __forceinline__ float fast_tanh(float x) {
    x = fminf(12.0f, fmaxf(-12.0f, x));
    float e = __expf(2.0f * x);
    return (e - 1.0f) / (e + 1.0f);
}

// physical byte offset of logical A-frag slot (bank-conflict swizzle)
__device__ __forceinline__ int swzb(int slot) {
    return (slot << 4) ^ (((slot >> 2) & 1) << 5);
}

// ---------------------------------------------------------------------------
// One pipelined launch: role A = h1 chain chunk k; role G = z GEMM chunk k-1;
// role B = h2 chain chunk k-2.  No cross-WG sync anywhere: the kernel-launch
// boundary is the barrier (device-scope visibility guaranteed by the stream).
// ---------------------------------------------------------------------------
extern "C" __global__ __launch_bounds__(256, 1)
void chunk_kernel(int k,
                  const float* __restrict__ x,
                  const float* __restrict__ eWih0, const float* __restrict__ eWhh0,
                  const float* __restrict__ ebih0, const float* __restrict__ ebhh0,
                  const float* __restrict__ eWih1, const float* __restrict__ eWhh1,
                  const float* __restrict__ ebih1, const float* __restrict__ ebhh1,
                  char* __restrict__ ws)
{
    extern __shared__ char lds[];
    char*  h1buf = ws + H1BUF_OFF;
    char*  zbuf  = ws + ZBUF_OFF;
    char*  hsave = ws + HSAVE_OFF;
    float* enc   = (float*)(ws + ENC_OFF);

    const int blk  = blockIdx.x;
    const int role = blk >> 4;     // 0=A, 1=B, 2=G
    const int g    = blk & 15;
    const int tid  = threadIdx.x;
    const int wq   = tid >> 6;
    const int l    = tid & 63;
    const int lm   = l & 15;
    const int q    = l >> 4;
    const int rdoff = (l << 4) ^ (((l >> 2) & 1) << 5);  // swizzled read byte off
    const int rho   = l ^ (((l >> 2) & 1) << 1);         // logical slot at phys slot l

    if (role <= 1) {
        // ================= chain roles (A: layer-0, B: layer-1) =================
        const bool isA = (role == 0);
        if (isA) { if (k >= NCH) return; }
        else     { if (k < 2)    return; }
        const int c = isA ? k : k - 2;
        const float* Whh = isA ? eWhh0 : eWhh1;

        char* HS = lds;            // [0,32768) h-state double buffer
        char* WL = lds + 32768;    // [32768,163840) 4 K-steps of B-frags

        // ---- state init: zero (first chunk) or reload raw 16 KB ----
        if (c == 0) {
            bf16x8 z8;
#pragma unroll
            for (int j = 0; j < 8; ++j) z8[j] = (__bf16)0.f;
            for (int o = tid; o < 1024; o += 256) *(bf16x8*)(HS + o * 16) = z8;
        } else {
            const char* src = hsave + (size_t)(role * 16 + g) * 16384;
#pragma unroll
            for (int r = 0; r < 4; ++r)
                *(f32x4*)(HS + (tid * 4 + r) * 16) = *(const f32x4*)(src + (tid * 4 + r) * 16);
        }

        // ---- weights: 12 K-steps in VGPR, 4 in LDS ----
        bf16x8 WR[12][8];
        bf16x8 EB[8];
        float  bias[8];
#pragma unroll
        for (int n = 0; n < 8; ++n) {
            const int col = wq * 128 + n * 16 + lm;
            const float* wrow = Whh + (size_t)col * NH;
#pragma unroll
            for (int ks = 0; ks < 12; ++ks) {
                const float* p = wrow + ks * 32 + q * 8;
#pragma unroll
                for (int j = 0; j < 8; ++j) WR[ks][n][j] = (__bf16)p[j];
            }
#pragma unroll
            for (int ks = 12; ks < 16; ++ks) {
                const float* p = wrow + ks * 32 + q * 8;
                bf16x8 tmp;
#pragma unroll
                for (int j = 0; j < 8; ++j) tmp[j] = (__bf16)p[j];
                *(bf16x8*)(WL + (((ks - 12) * 32 + wq * 8 + n) * 64 + l) * 16) = tmp;
            }
#pragma unroll
            for (int j = 0; j < 8; ++j) EB[n][j] = (__bf16)0.f;
            if (isA) {
                if (q == 0) {
                    const float4 w0 = *(const float4*)(eWih0 + (size_t)col * NV);
                    EB[n][0] = (__bf16)w0.x; EB[n][1] = (__bf16)w0.y;
                    EB[n][2] = (__bf16)w0.z; EB[n][3] = (__bf16)w0.w;
                }
                bias[n] = ebih0[col] + ebhh0[col];
            } else {
                bias[n] = 0.f;  // z already contains layer-1 biases
            }
        }
        __syncthreads();

        char* rsl = h1buf + (size_t)((g * 2 + (c & 1)) * CH) * 16384;  // A writes
        char* zsl = zbuf  + (size_t)((g * 2 + (c & 1)) * CH) * 32768;  // B reads

        f32x4 zn[8];
        if (!isA) {
#pragma unroll
            for (int n = 0; n < 8; ++n)
                zn[n] = *(const f32x4*)(zsl + ((wq * 8 + n) * 64 + l) * 16);
        }

#pragma unroll 1
        for (int t = 0; t < CH; ++t) {
            const int i  = c * CH + t;
            const int rb = t & 1;
            const char* hsr = HS + rb * 16384;
            char*       hsw = HS + (rb ^ 1) * 16384;

            f32x4 acc[8];
            bf16x8 xa;
            if (isA) {
#pragma unroll
                for (int n = 0; n < 8; ++n)
                    acc[n] = (f32x4){bias[n], bias[n], bias[n], bias[n]};
                const float4 xv = *(const float4*)(x + ((size_t)(g * 16 + lm) * NS + i) * NV);
#pragma unroll
                for (int j = 0; j < 8; ++j) xa[j] = (__bf16)0.f;
                if (q == 0) {
                    xa[0] = (__bf16)xv.x; xa[1] = (__bf16)xv.y;
                    xa[2] = (__bf16)xv.z; xa[3] = (__bf16)xv.w;
                }
            } else {
#pragma unroll
                for (int n = 0; n < 8; ++n) acc[n] = zn[n];
                if (t + 1 < CH) {
#pragma unroll
                    for (int n = 0; n < 8; ++n)
                        zn[n] = *(const f32x4*)(zsl + (size_t)(t + 1) * 32768 +
                                                ((wq * 8 + n) * 64 + l) * 16);
                }
            }

            // ---- 16 main K-steps ----
#pragma unroll
            for (int ks = 0; ks < 12; ++ks) {
                const bf16x8 af = *(const bf16x8*)(hsr + ks * 1024 + rdoff);
#pragma unroll
                for (int n = 0; n < 8; ++n)
                    acc[n] = __builtin_amdgcn_mfma_f32_16x16x32_bf16(af, WR[ks][n], acc[n], 0, 0, 0);
            }
#pragma unroll
            for (int ks = 12; ks < 16; ++ks) {
                const bf16x8 af = *(const bf16x8*)(hsr + ks * 1024 + rdoff);
#pragma unroll
                for (int n = 0; n < 8; ++n) {
                    const bf16x8 bf = *(const bf16x8*)(WL + (((ks - 12) * 32 + wq * 8 + n) * 64 + l) * 16);
                    acc[n] = __builtin_amdgcn_mfma_f32_16x16x32_bf16(af, bf, acc[n], 0, 0, 0);
                }
            }
            if (isA) {  // x @ Wih0^T (extension K-step)
#pragma unroll
                for (int n = 0; n < 8; ++n)
                    acc[n] = __builtin_amdgcn_mfma_f32_16x16x32_bf16(xa, EB[n], acc[n], 0, 0, 0);
            }

            // ---- epilogue ----
            if (!isA && i == NS - 1) {
                // encoded = PRE-tanh (arctanh(tanh(s)) == s)
#pragma unroll
                for (int n = 0; n < 8; ++n) {
                    const int col = wq * 128 + n * 16 + lm;
#pragma unroll
                    for (int jr = 0; jr < 4; ++jr)
                        enc[(size_t)(g * 16 + q * 4 + jr) * NH + col] = acc[n][jr];
                }
            } else {
#pragma unroll
                for (int n = 0; n < 8; ++n) {
                    const int col = wq * 128 + n * 16 + lm;
                    const int ks  = col >> 5;
                    const int cq  = (col >> 3) & 3;
                    const int bo  = (col & 7) * 2;
#pragma unroll
                    for (int jr = 0; jr < 4; ++jr) {
                        const float th = fast_tanh(acc[n][jr]);
                        const int slot = (q * 4 + jr) | (cq << 4);
                        *(__bf16*)(hsw + ks * 1024 + swzb(slot) + bo) = (__bf16)th;
                    }
                }
            }
            __syncthreads();  // hsw complete for all waves

            if (isA) {
                // copy new h1 (LDS, swizzled) -> h1buf (global, logical-linear)
                char* rdst = rsl + (size_t)t * 16384;
#pragma unroll
                for (int kk = 0; kk < 4; ++kk) {
                    const int ks = wq * 4 + kk;
                    const bf16x8 v = *(const bf16x8*)(hsw + ks * 1024 + l * 16);
                    *(bf16x8*)(rdst + ks * 1024 + rho * 16) = v;
                }
            }
        }

        // ---- raw state save (buf0 holds the boundary state; CH is even) ----
        {
            char* dst = hsave + (size_t)(role * 16 + g) * 16384;
#pragma unroll
            for (int r = 0; r < 4; ++r)
                *(f32x4*)(dst + (tid * 4 + r) * 16) = *(const f32x4*)(HS + (tid * 4 + r) * 16);
        }
    } else {
        // ================= G role: z[c] = h1[c] @ Wih1^T + bias =================
        if (k < 1 || k > NCH) return;
        const int c = k - 1;
        const char* rsl = h1buf + (size_t)((g * 2 + (c & 1)) * CH) * 16384;
        char*       zsl = zbuf  + (size_t)((g * 2 + (c & 1)) * CH) * 32768;

#pragma unroll 1
        for (int nb = 0; nb < 4; ++nb) {
            // stage Wih1 cols [nb*128, nb*128+128) as B-frags: [ks16][n8][l64][16B]
            for (int idx = tid; idx < 8192; idx += 256) {
                const int ks = idx >> 9, n = (idx >> 6) & 7, ll = idx & 63;
                const int col = nb * 128 + n * 16 + (ll & 15);
                const float* p = eWih1 + (size_t)col * NH + ks * 32 + ((ll >> 4) << 3);
                bf16x8 tmp;
#pragma unroll
                for (int j = 0; j < 8; ++j) tmp[j] = (__bf16)p[j];
                *(bf16x8*)(lds + (size_t)idx * 16) = tmp;
            }
            float bvn[8];
#pragma unroll
            for (int n = 0; n < 8; ++n) {
                const int col = nb * 128 + n * 16 + lm;
                bvn[n] = ebih1[col] + ebhh1[col];
            }
            __syncthreads();

            f32x4 acc[4][8];
#pragma unroll
            for (int tt = 0; tt < 4; ++tt)
#pragma unroll
                for (int n = 0; n < 8; ++n) acc[tt][n] = (f32x4){0.f, 0.f, 0.f, 0.f};

#pragma unroll 1
            for (int ks = 0; ks < 16; ++ks) {
                bf16x8 af[4];
#pragma unroll
                for (int tt = 0; tt < 4; ++tt)
                    af[tt] = *(const bf16x8*)(rsl + (size_t)(wq * 4 + tt) * 16384 + ks * 1024 + l * 16);
#pragma unroll
                for (int n = 0; n < 8; ++n) {
                    const bf16x8 bfr = *(const bf16x8*)(lds + (size_t)((ks * 8 + n) * 64 + l) * 16);
#pragma unroll
                    for (int tt = 0; tt < 4; ++tt)
                        acc[tt][n] = __builtin_amdgcn_mfma_f32_16x16x32_bf16(af[tt], bfr, acc[tt][n], 0, 0, 0);
                }
            }

#pragma unroll
            for (int tt = 0; tt < 4; ++tt)
#pragma unroll
                for (int n = 0; n < 8; ++n) {
                    f32x4 v = acc[tt][n];
                    v[0] += bvn[n]; v[1] += bvn[n]; v[2] += bvn[n]; v[3] += bvn[n];
                    *(f32x4*)(zsl + (size_t)(wq * 4 + tt) * 32768 + ((nb * 8 + n) * 64 + l) * 16) = v;
                }
            __syncthreads();  // protect LDS before next stage
        }
    }
}

// ---------------------------------------------------------------------------
// Batch-axis softmax stats per hidden column.
// ---------------------------------------------------------------------------
__global__ void colstats_kernel(const float* __restrict__ encoded,
                                float* __restrict__ colmax,
                                float* __restrict__ rsinv)
{
    const int h = blockIdx.x;
    const int lane = threadIdx.x;  // 64
    float v[4];
#pragma unroll
    for (int r = 0; r < 4; ++r) v[r] = encoded[(size_t)(lane + 64 * r) * NH + h];
    float mx = fmaxf(fmaxf(v[0], v[1]), fmaxf(v[2], v[3]));
#pragma unroll
    for (int s = 1; s < 64; s <<= 1) mx = fmaxf(mx, __shfl_xor(mx, s));
    float sum = 0.f;
#pragma unroll
    for (int r = 0; r < 4; ++r) sum += __expf(v[r] - mx);
#pragma unroll
    for (int s = 1; s < 64; s <<= 1) sum += __shfl_xor(sum, s);
    if (lane == 0) { colmax[h] = mx; rsinv[h] = 1.0f / sum; }
}

// ---------------------------------------------------------------------------
// Decoder: 16 WGs x 1 wave; lane = 4*local_batch + j.
// ---------------------------------------------------------------------------
__global__ void decoder_kernel(
    const float* __restrict__ encoded,
    const float* __restrict__ colmax, const float* __restrict__ rsinv,
    const float* __restrict__ dWih0, const float* __restrict__ dWhh0,
    const float* __restrict__ dbih0, const float* __restrict__ dbhh0,
    const float* __restrict__ dWih1, const float* __restrict__ dWhh1,
    const float* __restrict__ dbih1, const float* __restrict__ dbhh1,
    float* __restrict__ out)
{
    const int lane = threadIdx.x;  // 64
    const int bl = lane >> 2, j = lane & 3;
    const int b = blockIdx.x * 16 + bl;

    float a1 = dbih0[j];
    const float* er = encoded + (size_t)b * NH;
    const float* wr = dWih0 + (size_t)j * NH;
    for (int h = 0; h < NH; ++h)
        a1 += __expf(er[h] - colmax[h]) * rsinv[h] * wr[h];

    const float4 Whh0r = *(const float4*)(dWhh0 + j * 4);
    const float4 Wih1r = *(const float4*)(dWih1 + j * 4);
    const float4 Whh1r = *(const float4*)(dWhh1 + j * 4);
    const float c1 = a1 + dbhh0[j];
    const float c2 = dbih1[j] + dbhh1[j];
    float h1 = 0.f, h2 = 0.f;
    const int base = lane & ~3;
    float* op = out + (size_t)b * NS * NV + j;

#pragma unroll 1
    for (int t = 0; t < NS; ++t) {
        float s = c1;
        s += Whh0r.x * __shfl(h1, base + 0);
        s += Whh0r.y * __shfl(h1, base + 1);
        s += Whh0r.z * __shfl(h1, base + 2);
        s += Whh0r.w * __shfl(h1, base + 3);
        h1 = fast_tanh(s);
        float s2 = c2;
        s2 += Wih1r.x * __shfl(h1, base + 0) + Whh1r.x * __shfl(h2, base + 0);
        s2 += Wih1r.y * __shfl(h1, base + 1) + Whh1r.y * __shfl(h2, base + 1);
        s2 += Wih1r.z * __shfl(h1, base + 2) + Whh1r.z * __shfl(h2, base + 2);
        s2 += Wih1r.w * __shfl(h1, base + 3) + Whh1r.w * __shfl(h2, base + 3);
        h2 = fast_tanh(s2);
        op[(size_t)t * NV] = h2;
    }
}

extern "C" void kernel_launch(void* const* d_in, const int* in_sizes, int n_in,
                              void* d_out, int out_size, void* d_ws, size_t ws_size,
                              hipStream_t stream)
{
    const float* x     = (const float*)d_in[0];
    const float* eWih0 = (const float*)d_in[1];
    const float* eWhh0 = (const float*)d_in[2];
    const float* ebih0 = (const float*)d_in[3];
    const float* ebhh0 = (const float*)d_in[4];
    const float* eWih1 = (const float*)d_in[5];
    const float* eWhh1 = (const float*)d_in[6];
    const float* ebih1 = (const float*)d_in[7];
    const float* ebhh1 = (const float*)d_in[8];
    const float* dWih0 = (const float*)d_in[9];
    const float* dWhh0 = (const float*)d_in[10];
    const float* dbih0 = (const float*)d_in[11];
    const float* dbhh0 = (const float*)d_in[12];
    const float* dWih1 = (const float*)d_in[13];
    const float* dWhh1 = (const float*)d_in[14];
    const float* dbih1 = (const float*)d_in[15];
    const float* dbhh1 = (const float*)d_in[16];

    char*  ws     = (char*)d_ws;
    float* enc    = (float*)(ws + ENC_OFF);
    float* colmax = (float*)(ws + CM_OFF);
    float* rsinv  = (float*)(ws + RS_OFF);

    hipFuncSetAttribute((const void*)chunk_kernel,
                        hipFuncAttributeMaxDynamicSharedMemorySize, 163840);

    // software pipeline across launch boundaries: A(k) || G(k-1) || B(k-2)
    for (int k = 0; k < NCH + 2; ++k)
        chunk_kernel<<<48, 256, 163840, stream>>>(k, x,
                                                  eWih0, eWhh0, ebih0, ebhh0,
                                                  eWih1, eWhh1, ebih1, ebhh1, ws);

    colstats_kernel<<<NH, 64, 0, stream>>>(enc, colmax, rsinv);
    decoder_kernel<<<16, 64, 0, stream>>>(enc, colmax, rsinv,
                                          dWih0, dWhh0, dbih0, dbhh0,
                                          dWih1, dWhh1, dbih1, dbhh1,
                                          (float*)d_out);
}

// Round 4
// 2889.452 us; speedup vs baseline: 6.1021x; 2.0289x over previous
//
#include <hip/hip_runtime.h>
#include <hip/hip_bf16.h>

#define NB 256   // batch
#define NS 512   // seq len
#define NV 4     // vocab
#define NH 512   // encoder hidden
#define CH 16    // steps per chunk
#define NCH 32   // chunks

typedef __bf16 bf16x8 __attribute__((ext_vector_type(8)));
typedef float  f32x4  __attribute__((ext_vector_type(4)));

// ---- workspace byte offsets ----
// h1buf: [g][parity][t][ks16][slot64][16B]  8 MB
// zbuf : [g][parity][t][gt32][l64][16B]     16 MB (f32x4)
// hsave: [role][g] 16KB raw LDS state       512 KB
// enc  : [B][H] f32                         512 KB
// frag : 3 x 512KB bf16 B-frags (Whh0, Whh1, Wih1), layout [ks16][gt32][l64][16B]
#define H1BUF_OFF  0
#define ZBUF_OFF   (8u << 20)
#define HSAVE_OFF  (24u << 20)
#define ENC_OFF    ((24u << 20) + (1u << 19))
#define CM_OFF     (ENC_OFF + NB*NH*4)
#define RS_OFF     (CM_OFF + 2048)
#define FRAG_OFF   (RS_OFF + 2048)

__device__ __forceinline__ float fast_tanh(float x) {
    x = fminf(12.0f, fmaxf(-12.0f, x));
    float e = __expf(2.0f * x);
    return (e - 1.0f) / (e + 1.0f);
}

// physical byte offset of logical A-frag slot (bank-conflict swizzle)
__device__ __forceinline__ int swzb(int slot) {
    return (slot << 4) ^ (((slot >> 2) & 1) << 5);
}

// ---------------------------------------------------------------------------
// One-shot: re-lay weight matrices as bf16 MFMA B-fragments.
// frag[mt] layout: ((ks*32 + gt)*64 + l)*16 bytes, gt = n-tile 0..31.
// ---------------------------------------------------------------------------
__global__ void prep_kernel(const float* __restrict__ W0, const float* __restrict__ W1,
                            const float* __restrict__ WG, char* __restrict__ ws)
{
    const int mt = blockIdx.x >> 5;     // 0=Whh0, 1=Whh1, 2=Wih1
    const int gt = blockIdx.x & 31;
    const float* src = (mt == 0) ? W0 : (mt == 1) ? W1 : WG;
    char* dst = ws + FRAG_OFF + (size_t)mt * (1u << 19);
    const int tid = threadIdx.x;
#pragma unroll
    for (int s = 0; s < 4; ++s) {
        const int e  = tid + s * 256;    // 0..1023
        const int ks = e >> 6, ll = e & 63;
        const int col = gt * 16 + (ll & 15);
        const float* p = src + (size_t)col * NH + ks * 32 + ((ll >> 4) << 3);
        bf16x8 v;
#pragma unroll
        for (int j = 0; j < 8; ++j) v[j] = (__bf16)p[j];
        *(bf16x8*)(dst + ((size_t)(ks * 32 + gt) * 64 + ll) * 16) = v;
    }
}

// ---------------------------------------------------------------------------
// Pipelined launch: role A = h1 chain chunk k; role G = z GEMM chunk k-1;
// role B = h2 chain chunk k-2.  512 threads / 8 waves; each chain wave owns
// 64 cols -> weight frags fit in 192 VGPRs (no spills) + 4 K-slabs in LDS.
// ---------------------------------------------------------------------------
extern "C" __global__ __launch_bounds__(512, 2)
void chunk_kernel(int k,
                  const float* __restrict__ x,
                  const float* __restrict__ eWih0,
                  const float* __restrict__ ebih0, const float* __restrict__ ebhh0,
                  const float* __restrict__ ebih1, const float* __restrict__ ebhh1,
                  char* __restrict__ ws)
{
    extern __shared__ char lds[];
    char*  h1buf = ws + H1BUF_OFF;
    char*  zbuf  = ws + ZBUF_OFF;
    char*  hsave = ws + HSAVE_OFF;
    float* enc   = (float*)(ws + ENC_OFF);
    const char* fragA = ws + FRAG_OFF;                 // Whh0
    const char* fragB = ws + FRAG_OFF + (1u << 19);    // Whh1
    const char* fragG = ws + FRAG_OFF + (2u << 19);    // Wih1

    const int blk  = blockIdx.x;
    const int role = blk >> 4;     // 0=A, 1=B, 2=G
    const int g    = blk & 15;
    const int tid  = threadIdx.x;
    const int wq   = tid >> 6;     // wave 0..7
    const int l    = tid & 63;
    const int lm   = l & 15;
    const int q    = l >> 4;
    const int rdoff = (l << 4) ^ (((l >> 2) & 1) << 5);  // swizzled A-frag read

    if (role <= 1) {
        // ================= chain roles (A: layer-0, B: layer-1) =================
        const bool isA = (role == 0);
        if (isA) { if (k >= NCH) return; }
        else     { if (k < 2)    return; }
        const int c = isA ? k : k - 2;
        const char* frag = isA ? fragA : fragB;

        char* HS = lds;            // [0,32768) h-state double buffer
        char* WL = lds + 32768;    // [32768,163840) K-steps 12..15 B-frags

        // ---- state init ----
        if (c == 0) {
            bf16x8 z8;
#pragma unroll
            for (int j = 0; j < 8; ++j) z8[j] = (__bf16)0.f;
            for (int o = tid; o < 1024; o += 512) *(bf16x8*)(HS + o * 16) = z8;
        } else {
            const char* src = hsave + (size_t)(role * 16 + g) * 16384;
#pragma unroll
            for (int r = 0; r < 2; ++r)
                *(f32x4*)(HS + (tid * 2 + r) * 16) = *(const f32x4*)(src + (tid * 2 + r) * 16);
        }

        // ---- weights: 12 K-steps in VGPR (192 regs), 4 in LDS ----
        bf16x8 WR[12][4];
#pragma unroll
        for (int ks = 0; ks < 12; ++ks)
#pragma unroll
            for (int n = 0; n < 4; ++n)
                WR[ks][n] = *(const bf16x8*)(frag + ((size_t)(ks * 32 + wq * 4 + n) * 64 + l) * 16);
#pragma unroll
        for (int ks = 12; ks < 16; ++ks)
#pragma unroll
            for (int n = 0; n < 4; ++n) {
                const bf16x8 v = *(const bf16x8*)(frag + ((size_t)(ks * 32 + wq * 4 + n) * 64 + l) * 16);
                *(bf16x8*)(WL + (((ks - 12) * 32 + wq * 4 + n) * 64 + l) * 16) = v;
            }

        bf16x8 EB[4];
        float  bias[4];
#pragma unroll
        for (int n = 0; n < 4; ++n) {
            const int col = wq * 64 + n * 16 + lm;
#pragma unroll
            for (int j = 0; j < 8; ++j) EB[n][j] = (__bf16)0.f;
            if (isA) {
                if (q == 0) {
                    const float4 w0 = *(const float4*)(eWih0 + (size_t)col * NV);
                    EB[n][0] = (__bf16)w0.x; EB[n][1] = (__bf16)w0.y;
                    EB[n][2] = (__bf16)w0.z; EB[n][3] = (__bf16)w0.w;
                }
                bias[n] = ebih0[col] + ebhh0[col];
            } else {
                bias[n] = 0.f;  // z already contains layer-1 biases
            }
        }
        __syncthreads();

        char* rsl = h1buf + (size_t)((g * 2 + (c & 1)) * CH) * 16384;  // A writes
        char* zsl = zbuf  + (size_t)((g * 2 + (c & 1)) * CH) * 32768;  // B reads

        f32x4 zn[4];
        if (!isA) {
#pragma unroll
            for (int n = 0; n < 4; ++n)
                zn[n] = *(const f32x4*)(zsl + ((wq * 4 + n) * 64 + l) * 16);
        }

#pragma unroll 1
        for (int t = 0; t < CH; ++t) {
            const int i  = c * CH + t;
            const int rb = t & 1;
            const char* hsr = HS + rb * 16384;
            char*       hsw = HS + (rb ^ 1) * 16384;

            f32x4 acc[4];
            bf16x8 xa;
            if (isA) {
#pragma unroll
                for (int n = 0; n < 4; ++n)
                    acc[n] = (f32x4){bias[n], bias[n], bias[n], bias[n]};
                const float4 xv = *(const float4*)(x + ((size_t)(g * 16 + lm) * NS + i) * NV);
#pragma unroll
                for (int j = 0; j < 8; ++j) xa[j] = (__bf16)0.f;
                if (q == 0) {
                    xa[0] = (__bf16)xv.x; xa[1] = (__bf16)xv.y;
                    xa[2] = (__bf16)xv.z; xa[3] = (__bf16)xv.w;
                }
            } else {
#pragma unroll
                for (int n = 0; n < 4; ++n) acc[n] = zn[n];
                if (t + 1 < CH) {
#pragma unroll
                    for (int n = 0; n < 4; ++n)
                        zn[n] = *(const f32x4*)(zsl + (size_t)(t + 1) * 32768 +
                                                ((wq * 4 + n) * 64 + l) * 16);
                }
            }

            // ---- K-steps ----
#pragma unroll
            for (int ks = 0; ks < 12; ++ks) {
                const bf16x8 af = *(const bf16x8*)(hsr + ks * 1024 + rdoff);
#pragma unroll
                for (int n = 0; n < 4; ++n)
                    acc[n] = __builtin_amdgcn_mfma_f32_16x16x32_bf16(af, WR[ks][n], acc[n], 0, 0, 0);
            }
#pragma unroll
            for (int ks = 12; ks < 16; ++ks) {
                const bf16x8 af = *(const bf16x8*)(hsr + ks * 1024 + rdoff);
#pragma unroll
                for (int n = 0; n < 4; ++n) {
                    const bf16x8 bfr = *(const bf16x8*)(WL + (((ks - 12) * 32 + wq * 4 + n) * 64 + l) * 16);
                    acc[n] = __builtin_amdgcn_mfma_f32_16x16x32_bf16(af, bfr, acc[n], 0, 0, 0);
                }
            }
            if (isA) {  // x @ Wih0^T extension K-step
#pragma unroll
                for (int n = 0; n < 4; ++n)
                    acc[n] = __builtin_amdgcn_mfma_f32_16x16x32_bf16(xa, EB[n], acc[n], 0, 0, 0);
            }

            // ---- epilogue ----
            if (!isA && i == NS - 1) {
                // encoded = PRE-tanh (arctanh(tanh(s)) == s)
#pragma unroll
                for (int n = 0; n < 4; ++n) {
                    const int col = wq * 64 + n * 16 + lm;
#pragma unroll
                    for (int jr = 0; jr < 4; ++jr)
                        enc[(size_t)(g * 16 + q * 4 + jr) * NH + col] = acc[n][jr];
                }
            } else {
#pragma unroll
                for (int n = 0; n < 4; ++n) {
                    const int col = wq * 64 + n * 16 + lm;
                    const int ks  = col >> 5;
                    const int cq  = (col >> 3) & 3;
                    const int bo  = (col & 7) * 2;
#pragma unroll
                    for (int jr = 0; jr < 4; ++jr) {
                        const float th = fast_tanh(acc[n][jr]);
                        const int slot = (q * 4 + jr) | (cq << 4);
                        *(__bf16*)(hsw + ks * 1024 + swzb(slot) + bo) = (__bf16)th;
                    }
                }
            }
            __syncthreads();  // hsw complete for all waves

            if (isA) {
                // copy new h1 (LDS swizzled) -> h1buf (global, logical-linear)
                char* rdst = rsl + (size_t)t * 16384;
#pragma unroll
                for (int e = tid; e < 1024; e += 512) {
                    const int ks = e >> 6, slot = e & 63;
                    const bf16x8 v = *(const bf16x8*)(hsw + ks * 1024 + swzb(slot));
                    *(bf16x8*)(rdst + ks * 1024 + slot * 16) = v;
                }
            }
        }

        // ---- raw state save (buffer 0 holds boundary state; CH even) ----
        {
            char* dst = hsave + (size_t)(role * 16 + g) * 16384;
#pragma unroll
            for (int r = 0; r < 2; ++r)
                *(f32x4*)(dst + (tid * 2 + r) * 16) = *(const f32x4*)(HS + (tid * 2 + r) * 16);
        }
    } else {
        // ================= G role: z[c] = h1[c] @ Wih1^T + bias =================
        if (k < 1 || k > NCH) return;
        const int c = k - 1;
        const char* rsl = h1buf + (size_t)((g * 2 + (c & 1)) * CH) * 16384;
        char*       zsl = zbuf  + (size_t)((g * 2 + (c & 1)) * CH) * 32768;

#pragma unroll 1
        for (int nb = 0; nb < 4; ++nb) {
            // stage 8 n-tiles (128 cols, full K) of pre-fragged Wih1: 128 KB
#pragma unroll
            for (int s = 0; s < 16; ++s) {
                const int idx = tid + s * 512;        // 0..8191
                const int ks = idx >> 9, r = idx & 511;
                *(bf16x8*)(lds + (size_t)idx * 16) =
                    *(const bf16x8*)(fragG + ((size_t)(ks * 32 + nb * 8) * 64 + r) * 16);
            }
            float bvn[8];
#pragma unroll
            for (int n = 0; n < 8; ++n) {
                const int col = nb * 128 + n * 16 + lm;
                bvn[n] = ebih1[col] + ebhh1[col];
            }
            __syncthreads();

            f32x4 acc[2][8];
#pragma unroll
            for (int tt = 0; tt < 2; ++tt)
#pragma unroll
                for (int n = 0; n < 8; ++n) acc[tt][n] = (f32x4){0.f, 0.f, 0.f, 0.f};

#pragma unroll 1
            for (int ks = 0; ks < 16; ++ks) {
                const bf16x8 af0 = *(const bf16x8*)(rsl + (size_t)(wq * 2 + 0) * 16384 + ks * 1024 + l * 16);
                const bf16x8 af1 = *(const bf16x8*)(rsl + (size_t)(wq * 2 + 1) * 16384 + ks * 1024 + l * 16);
#pragma unroll
                for (int n = 0; n < 8; ++n) {
                    const bf16x8 bfr = *(const bf16x8*)(lds + (size_t)((ks * 8 + n) * 64 + l) * 16);
                    acc[0][n] = __builtin_amdgcn_mfma_f32_16x16x32_bf16(af0, bfr, acc[0][n], 0, 0, 0);
                    acc[1][n] = __builtin_amdgcn_mfma_f32_16x16x32_bf16(af1, bfr, acc[1][n], 0, 0, 0);
                }
            }

#pragma unroll
            for (int tt = 0; tt < 2; ++tt)
#pragma unroll
                for (int n = 0; n < 8; ++n) {
                    f32x4 v = acc[tt][n];
                    v[0] += bvn[n]; v[1] += bvn[n]; v[2] += bvn[n]; v[3] += bvn[n];
                    *(f32x4*)(zsl + (size_t)(wq * 2 + tt) * 32768 + ((nb * 8 + n) * 64 + l) * 16) = v;
                }
            __syncthreads();  // protect LDS before next stage
        }
    }
}

// ---------------------------------------------------------------------------
// Batch-axis softmax stats per hidden column.
// ---------------------------------------------------------------------------
__global__ void colstats_kernel(const float* __restrict__ encoded,
                                float* __restrict__ colmax,
                                float* __restrict__ rsinv)
{
    const int h = blockIdx.x;
    const int lane = threadIdx.x;  // 64
    float v[4];
#pragma unroll
    for (int r = 0; r < 4; ++r) v[r] = encoded[(size_t)(lane + 64 * r) * NH + h];
    float mx = fmaxf(fmaxf(v[0], v[1]), fmaxf(v[2], v[3]));
#pragma unroll
    for (int s = 1; s < 64; s <<= 1) mx = fmaxf(mx, __shfl_xor(mx, s));
    float sum = 0.f;
#pragma unroll
    for (int r = 0; r < 4; ++r) sum += __expf(v[r] - mx);
#pragma unroll
    for (int s = 1; s < 64; s <<= 1) sum += __shfl_xor(sum, s);
    if (lane == 0) { colmax[h] = mx; rsinv[h] = 1.0f / sum; }
}

// ---------------------------------------------------------------------------
// Decoder: 16 WGs x 1 wave; lane = 4*local_batch + j.
// ---------------------------------------------------------------------------
__global__ void decoder_kernel(
    const float* __restrict__ encoded,
    const float* __restrict__ colmax, const float* __restrict__ rsinv,
    const float* __restrict__ dWih0, const float* __restrict__ dWhh0,
    const float* __restrict__ dbih0, const float* __restrict__ dbhh0,
    const float* __restrict__ dWih1, const float* __restrict__ dWhh1,
    const float* __restrict__ dbih1, const float* __restrict__ dbhh1,
    float* __restrict__ out)
{
    const int lane = threadIdx.x;  // 64
    const int bl = lane >> 2, j = lane & 3;
    const int b = blockIdx.x * 16 + bl;

    float a1 = dbih0[j];
    const float* er = encoded + (size_t)b * NH;
    const float* wr = dWih0 + (size_t)j * NH;
    for (int h = 0; h < NH; ++h)
        a1 += __expf(er[h] - colmax[h]) * rsinv[h] * wr[h];

    const float4 Whh0r = *(const float4*)(dWhh0 + j * 4);
    const float4 Wih1r = *(const float4*)(dWih1 + j * 4);
    const float4 Whh1r = *(const float4*)(dWhh1 + j * 4);
    const float c1 = a1 + dbhh0[j];
    const float c2 = dbih1[j] + dbhh1[j];
    float h1 = 0.f, h2 = 0.f;
    const int base = lane & ~3;
    float* op = out + (size_t)b * NS * NV + j;

#pragma unroll 1
    for (int t = 0; t < NS; ++t) {
        float s = c1;
        s += Whh0r.x * __shfl(h1, base + 0);
        s += Whh0r.y * __shfl(h1, base + 1);
        s += Whh0r.z * __shfl(h1, base + 2);
        s += Whh0r.w * __shfl(h1, base + 3);
        h1 = fast_tanh(s);
        float s2 = c2;
        s2 += Wih1r.x * __shfl(h1, base + 0) + Whh1r.x * __shfl(h2, base + 0);
        s2 += Wih1r.y * __shfl(h1, base + 1) + Whh1r.y * __shfl(h2, base + 1);
        s2 += Wih1r.z * __shfl(h1, base + 2) + Whh1r.z * __shfl(h2, base + 2);
        s2 += Wih1r.w * __shfl(h1, base + 3) + Whh1r.w * __shfl(h2, base + 3);
        h2 = fast_tanh(s2);
        op[(size_t)t * NV] = h2;
    }
}

extern "C" void kernel_launch(void* const* d_in, const int* in_sizes, int n_in,
                              void* d_out, int out_size, void* d_ws, size_t ws_size,
                              hipStream_t stream)
{
    const float* x     = (const float*)d_in[0];
    const float* eWih0 = (const float*)d_in[1];
    const float* eWhh0 = (const float*)d_in[2];
    const float* ebih0 = (const float*)d_in[3];
    const float* ebhh0 = (const float*)d_in[4];
    const float* eWih1 = (const float*)d_in[5];
    const float* eWhh1 = (const float*)d_in[6];
    const float* ebih1 = (const float*)d_in[7];
    const float* ebhh1 = (const float*)d_in[8];
    const float* dWih0 = (const float*)d_in[9];
    const float* dWhh0 = (const float*)d_in[10];
    const float* dbih0 = (const float*)d_in[11];
    const float* dbhh0 = (const float*)d_in[12];
    const float* dWih1 = (const float*)d_in[13];
    const float* dWhh1 = (const float*)d_in[14];
    const float* dbih1 = (const float*)d_in[15];
    const float* dbhh1 = (const float*)d_in[16];

    char*  ws     = (char*)d_ws;
    float* enc    = (float*)(ws + ENC_OFF);
    float* colmax = (float*)(ws + CM_OFF);
    float* rsinv  = (float*)(ws + RS_OFF);

    hipFuncSetAttribute((const void*)chunk_kernel,
                        hipFuncAttributeMaxDynamicSharedMemorySize, 163840);

    // one-shot weight fragmentation (bf16 B-frag layout)
    prep_kernel<<<96, 256, 0, stream>>>(eWhh0, eWhh1, eWih1, ws);

    // software pipeline across launch boundaries: A(k) || G(k-1) || B(k-2)
    for (int k = 0; k < NCH + 2; ++k)
        chunk_kernel<<<48, 512, 163840, stream>>>(k, x, eWih0,
                                                  ebih0, ebhh0, ebih1, ebhh1, ws);

    colstats_kernel<<<NH, 64, 0, stream>>>(enc, colmax, rsinv);
    decoder_kernel<<<16, 64, 0, stream>>>(enc, colmax, rsinv,
                                          dWih0, dWhh0, dbih0, dbhh0,
                                          dWih1, dWhh1, dbih1, dbhh1,
                                          (float*)d_out);
}